// Round 2
// baseline (151.944 us; speedup 1.0000x reference)
//
#include <hip/hip_runtime.h>
#include <math.h>

#define D_DIM 100000
#define W_DIM 128
#define BATCH 4096
#define CH    12288   // chunk floats = 48 KB LDS -> 3 blocks/CU resident
#define NCH   9       // ceil(100000/12288): 8 full chunks + tail of 1696

// Phase 1: stream each weight row through LDS in chunks; scan all batch
// indices; emit hits into transposed gather buffer GT[w][b] (coalesced).
// Grid: 2 matrices x 128 rows x 9 chunks = 2304 blocks.
__global__ __launch_bounds__(256) void gather_rows(
    const int* __restrict__ idx1, const int* __restrict__ idx2,
    const float* __restrict__ W1, const float* __restrict__ b1,
    const float* __restrict__ W2, const float* __restrict__ b2,
    float* __restrict__ G1T, float* __restrict__ G2T)
{
    __shared__ float lds[CH];

    const int bid = blockIdx.x;
    const int m   = bid / (W_DIM * NCH);     // which matrix
    const int rem = bid % (W_DIM * NCH);
    const int w   = rem / NCH;               // embedding row
    const int c   = rem % NCH;               // chunk

    const float* __restrict__ W   = m ? W2   : W1;
    const int*   __restrict__ idx = m ? idx2 : idx1;
    const float  bias             = m ? b2[w] : b1[w];
    float* __restrict__ GT        = m ? G2T  : G1T;

    const int base  = c * CH;
    const int limit = min(CH, D_DIM - base);   // floats in this chunk (div by 4)
    const float* src = W + (size_t)w * D_DIM + base;

    // Stream chunk into LDS: coalesced float4 (row base is 16B-aligned:
    // w*400000 and c*49152 are both multiples of 16).
    const int n4 = limit >> 2;
    const float4* __restrict__ src4 = (const float4*)src;
    float4* lds4 = (float4*)lds;
    for (int i = threadIdx.x; i < n4; i += 256)
        lds4[i] = src4[i];
    __syncthreads();

    // Scan all indices; ~BATCH/NCH of them land in this chunk.
    for (int b = threadIdx.x; b < BATCH; b += 256) {
        const int rel = idx[b] - base;
        if ((unsigned)rel < (unsigned)limit)
            GT[w * BATCH + b] = lds[rel] + bias;   // coalesced-in-b writes
    }
}

// Phase 2: dot over w (128) for each b, sigmoid, emit [1-s, s].
// 128 blocks x 256 threads: block covers 32 b's, 8 w-slices of 16.
__global__ __launch_bounds__(256) void dot_sig(
    const float* __restrict__ G1T, const float* __restrict__ G2T,
    float* __restrict__ out)
{
    __shared__ float red[8][32];
    const int bl = threadIdx.x & 31;   // b within tile
    const int sl = threadIdx.x >> 5;   // w slice
    const int b  = blockIdx.x * 32 + bl;

    float acc = 0.0f;
    #pragma unroll
    for (int k = 0; k < 16; ++k) {
        const int w = sl * 16 + k;
        acc += G1T[w * BATCH + b] * G2T[w * BATCH + b];
    }
    red[sl][bl] = acc;
    __syncthreads();

    if (sl == 0) {
        float v = 0.0f;
        #pragma unroll
        for (int s = 0; s < 8; ++s) v += red[s][bl];
        const float sgm = 1.0f / (1.0f + expf(-v));
        ((float2*)out)[b] = make_float2(1.0f - sgm, sgm);
    }
}

extern "C" void kernel_launch(void* const* d_in, const int* in_sizes, int n_in,
                              void* d_out, int out_size, void* d_ws, size_t ws_size,
                              hipStream_t stream)
{
    const int*   idx1 = (const int*)  d_in[0];
    const int*   idx2 = (const int*)  d_in[1];
    const float* W1   = (const float*)d_in[2];
    const float* b1   = (const float*)d_in[3];
    const float* W2   = (const float*)d_in[4];
    const float* b2   = (const float*)d_in[5];
    float* out = (float*)d_out;

    // Workspace: two transposed gather buffers [W_DIM][BATCH] = 2 MB each.
    float* G1T = (float*)d_ws;
    float* G2T = G1T + (size_t)W_DIM * BATCH;

    gather_rows<<<2 * W_DIM * NCH, 256, 0, stream>>>(idx1, idx2, W1, b1, W2, b2, G1T, G2T);
    dot_sig<<<BATCH / 32, 256, 0, stream>>>(G1T, G2T, out);
}

// Round 3
// 133.530 us; speedup vs baseline: 1.1379x; 1.1379x over previous
//
#include <hip/hip_runtime.h>
#include <math.h>

#define D_DIM 100000
#define W_DIM 128
#define BATCH 4096
#define NBUCK 6250   // line-granularity buckets: idx>>4
#define BPAD  7168   // 7 * 1024, padded counter array

// ---------------------------------------------------------------------------
// Kernel A: counting sort of (idx, b) by idx line (idx>>4). One block per
// matrix, 1024 threads. Output: packed[m][p] = (idx<<12)|b in ascending-line
// order. LDS: 28KB counters + 16KB ranks + 4KB scan = 48KB.
// ---------------------------------------------------------------------------
__global__ __launch_bounds__(1024) void bucket_sort(
    const int* __restrict__ idx1, const int* __restrict__ idx2,
    unsigned int* __restrict__ packed)
{
    __shared__ int cnt[BPAD];
    __shared__ int ranks[BATCH];
    __shared__ int psum[1024];

    const int m = blockIdx.x;
    const int* __restrict__ idx = m ? idx2 : idx1;
    const int t = threadIdx.x;

    for (int i = t; i < BPAD; i += 1024) cnt[i] = 0;
    __syncthreads();

    for (int i = t; i < BATCH; i += 1024)
        ranks[i] = atomicAdd(&cnt[idx[i] >> 4], 1);
    __syncthreads();

    // Blocked exclusive prefix sum over cnt[0..BPAD): 7 counters per thread.
    const int base = t * 7;
    int s = 0;
    #pragma unroll
    for (int j = 0; j < 7; ++j) s += cnt[base + j];
    psum[t] = s;
    __syncthreads();

    for (int off = 1; off < 1024; off <<= 1) {
        int v = (t >= off) ? psum[t - off] : 0;
        __syncthreads();
        psum[t] += v;
        __syncthreads();
    }

    int run = (t == 0) ? 0 : psum[t - 1];   // exclusive block offset
    #pragma unroll
    for (int j = 0; j < 7; ++j) {
        int c = cnt[base + j];
        cnt[base + j] = run;
        run += c;
    }
    __syncthreads();

    for (int i = t; i < BATCH; i += 1024) {
        const int v = idx[i];
        const int pos = cnt[v >> 4] + ranks[i];
        packed[m * BATCH + pos] = ((unsigned)v << 12) | (unsigned)i;
    }
}

// ---------------------------------------------------------------------------
// Kernel B: gather in sorted order. One wave per sorted entry; lane l loads
// W[l][i] and W[l+64][i] (+bias) and writes P[m][b][l], P[m][b][l+64]
// (coalesced 512B per wave). Block swizzle keeps each sorted chunk on one
// XCD so same-line reuse hits that XCD's L2.
// ---------------------------------------------------------------------------
__global__ __launch_bounds__(256) void gather(
    const unsigned int* __restrict__ packed,
    const float* __restrict__ W1, const float* __restrict__ b1,
    const float* __restrict__ W2, const float* __restrict__ b2,
    float* __restrict__ P)   // [2][BATCH][128]
{
    const int bid   = blockIdx.x;
    const int m     = bid >> 10;
    const int local = bid & 1023;
    // Dispatch round-robins XCDs by blockIdx: blocks with equal (local&7)
    // land on one XCD; give them a contiguous sorted range.
    const int nb = ((local & 7) << 7) | (local >> 3);
    const int p  = (nb << 2) + (threadIdx.x >> 6);
    const int l  = threadIdx.x & 63;

    const unsigned int pk = packed[(m << 12) + p];
    const int b = pk & 4095;
    const int i = (int)(pk >> 12);

    const float* __restrict__ W  = m ? W2 : W1;
    const float* __restrict__ bb = m ? b2 : b1;

    const float v0 = W[(size_t)l * D_DIM + i] + bb[l];
    const float v1 = W[(size_t)(l + 64) * D_DIM + i] + bb[l + 64];

    float* dst = P + (((size_t)(m << 12) + b) << 7);
    dst[l]      = v0;
    dst[l + 64] = v1;
}

// ---------------------------------------------------------------------------
// Kernel C: per-b dot over 128 dims + sigmoid. One wave per b; float2/lane.
// ---------------------------------------------------------------------------
__global__ __launch_bounds__(256) void dot_sig(
    const float* __restrict__ P, float* __restrict__ out)
{
    const int b = (blockIdx.x << 2) + (threadIdx.x >> 6);
    const int l = threadIdx.x & 63;

    const float2 x = ((const float2*)(P + ((size_t)b << 7)))[l];
    const float2 y = ((const float2*)(P + ((size_t)(BATCH + b) << 7)))[l];
    float v = x.x * y.x + x.y * y.y;

    #pragma unroll
    for (int off = 32; off > 0; off >>= 1)
        v += __shfl_down(v, off, 64);

    if (l == 0) {
        const float s = 1.0f / (1.0f + expf(-v));
        ((float2*)out)[b] = make_float2(1.0f - s, s);
    }
}

extern "C" void kernel_launch(void* const* d_in, const int* in_sizes, int n_in,
                              void* d_out, int out_size, void* d_ws, size_t ws_size,
                              hipStream_t stream)
{
    const int*   idx1 = (const int*)  d_in[0];
    const int*   idx2 = (const int*)  d_in[1];
    const float* W1   = (const float*)d_in[2];
    const float* b1   = (const float*)d_in[3];
    const float* W2   = (const float*)d_in[4];
    const float* b2   = (const float*)d_in[5];
    float* out = (float*)d_out;

    unsigned int* packed = (unsigned int*)d_ws;           // 2*4096*4 = 32 KB
    float* P = (float*)((char*)d_ws + 32768);             // 2*4096*128*4 = 4 MB

    bucket_sort<<<2, 1024, 0, stream>>>(idx1, idx2, packed);
    gather<<<2048, 256, 0, stream>>>(packed, W1, b1, W2, b2, P);
    dot_sig<<<BATCH / 4, 256, 0, stream>>>(P, out);
}

// Round 4
// 131.651 us; speedup vs baseline: 1.1541x; 1.0143x over previous
//
#include <hip/hip_runtime.h>
#include <math.h>

#define D_DIM 100000
#define W_DIM 128
#define BATCH 4096
#define BPAD  7168   // 7 * 1024 padded bucket counters; buckets = idx>>4 (6250 used)

// ---------------------------------------------------------------------------
// Kernel A: counting sort of (idx, b) by cache line (idx>>4). One block per
// matrix (2 blocks, 1024 threads). Hierarchical shuffle scan: 5 barriers.
// Output: packed[m][p] = (idx<<12)|b ascending in idx.
// ---------------------------------------------------------------------------
__global__ __launch_bounds__(1024) void bucket_sort(
    const int* __restrict__ idx1, const int* __restrict__ idx2,
    unsigned int* __restrict__ packed)
{
    __shared__ int cnt[BPAD];     // 28 KB
    __shared__ int ranks[BATCH];  // 16 KB
    __shared__ int wsum[16];

    const int m = blockIdx.x;
    const int* __restrict__ idx = m ? idx2 : idx1;
    const int t    = threadIdx.x;
    const int lane = t & 63;
    const int wv   = t >> 6;

    for (int i = t; i < BPAD; i += 1024) cnt[i] = 0;
    __syncthreads();

    #pragma unroll
    for (int j = 0; j < 4; ++j) {
        const int i = t + j * 1024;
        ranks[i] = atomicAdd(&cnt[idx[i] >> 4], 1);
    }
    __syncthreads();

    // Per-thread total over its 7 buckets, then wave shuffle-scan.
    const int base = t * 7;
    int c[7]; int s = 0;
    #pragma unroll
    for (int j = 0; j < 7; ++j) { c[j] = cnt[base + j]; s += c[j]; }

    int inc = s;
    #pragma unroll
    for (int off = 1; off < 64; off <<= 1) {
        const int v = __shfl_up(inc, off, 64);
        if (lane >= off) inc += v;
    }
    if (lane == 63) wsum[wv] = inc;
    __syncthreads();

    if (t < 16) {
        const int v = wsum[t];
        int winc = v;
        #pragma unroll
        for (int off = 1; off < 16; off <<= 1) {
            const int u = __shfl_up(winc, off, 16);
            if (t >= off) winc += u;
        }
        wsum[t] = winc - v;   // exclusive wave offset
    }
    __syncthreads();

    int excl = wsum[wv] + (inc - s);   // exclusive thread offset
    #pragma unroll
    for (int j = 0; j < 7; ++j) { cnt[base + j] = excl; excl += c[j]; }
    __syncthreads();

    #pragma unroll
    for (int j = 0; j < 4; ++j) {
        const int i = t + j * 1024;
        const int v = idx[i];
        packed[(m << 12) + cnt[v >> 4] + ranks[i]] =
            ((unsigned)v << 12) | (unsigned)i;
    }
}

// ---------------------------------------------------------------------------
// Kernel B: sorted gather. 1024 blocks x 256 threads; each wave handles TWO
// consecutive sorted entries (4 scattered loads in flight per lane).
// XCD k (bid&7) gets one contiguous 1024-entry sorted range -> L2 locality.
// ---------------------------------------------------------------------------
__global__ __launch_bounds__(256) void gather(
    const unsigned int* __restrict__ packed,
    const float* __restrict__ W1, const float* __restrict__ b1,
    const float* __restrict__ W2, const float* __restrict__ b2,
    float* __restrict__ P)   // [2][BATCH][128]
{
    const int bid = blockIdx.x;
    const int xcd = bid & 7;
    const int seq = bid >> 3;              // [0,128)
    const int wv  = threadIdx.x >> 6;
    const int l   = threadIdx.x & 63;

    // Global entry index e in [0, 8192): XCD k covers [k*1024, (k+1)*1024).
    const int e0 = (xcd << 10) + (seq << 3) + (wv << 1);
    const int m  = e0 >> 12;               // matrix (whole range same m)

    const float* __restrict__ W  = m ? W2 : W1;
    const float* __restrict__ bb = m ? b2 : b1;

    const unsigned pk0 = packed[e0];
    const unsigned pk1 = packed[e0 + 1];
    const int b0 = pk0 & 4095; const int i0 = (int)(pk0 >> 12);
    const int b1v = pk1 & 4095; const int i1 = (int)(pk1 >> 12);

    const float* colA = W + (size_t)l * D_DIM;
    const float* colB = W + (size_t)(l + 64) * D_DIM;
    const float a0 = colA[i0];
    const float a1 = colA[i1];
    const float a2 = colB[i0];
    const float a3 = colB[i1];

    const float biasA = bb[l];
    const float biasB = bb[l + 64];

    float* dst0 = P + (((size_t)(m << 12) + b0)  << 7);
    float* dst1 = P + (((size_t)(m << 12) + b1v) << 7);
    dst0[l]      = a0 + biasA;
    dst0[l + 64] = a2 + biasB;
    dst1[l]      = a1 + biasA;
    dst1[l + 64] = a3 + biasB;
}

// ---------------------------------------------------------------------------
// Kernel C: per-b dot over 128 dims + sigmoid. One wave per b (L2-hot P).
// ---------------------------------------------------------------------------
__global__ __launch_bounds__(256) void dot_sig(
    const float* __restrict__ P, float* __restrict__ out)
{
    const int b = (blockIdx.x << 2) + (threadIdx.x >> 6);
    const int l = threadIdx.x & 63;

    const float2 x = ((const float2*)(P + ((size_t)b << 7)))[l];
    const float2 y = ((const float2*)(P + ((size_t)(BATCH + b) << 7)))[l];
    float v = x.x * y.x + x.y * y.y;

    #pragma unroll
    for (int off = 32; off > 0; off >>= 1)
        v += __shfl_down(v, off, 64);

    if (l == 0) {
        const float s = 1.0f / (1.0f + expf(-v));
        ((float2*)out)[b] = make_float2(1.0f - s, s);
    }
}

extern "C" void kernel_launch(void* const* d_in, const int* in_sizes, int n_in,
                              void* d_out, int out_size, void* d_ws, size_t ws_size,
                              hipStream_t stream)
{
    const int*   idx1 = (const int*)  d_in[0];
    const int*   idx2 = (const int*)  d_in[1];
    const float* W1   = (const float*)d_in[2];
    const float* b1   = (const float*)d_in[3];
    const float* W2   = (const float*)d_in[4];
    const float* b2   = (const float*)d_in[5];
    float* out = (float*)d_out;

    unsigned int* packed = (unsigned int*)d_ws;        // 32 KB
    float* P = (float*)((char*)d_ws + 32768);          // 4 MB

    bucket_sort<<<2, 1024, 0, stream>>>(idx1, idx2, packed);
    gather<<<1024, 256, 0, stream>>>(packed, W1, b1, W2, b2, P);
    dot_sig<<<BATCH / 4, 256, 0, stream>>>(P, out);
}